// Round 4
// baseline (9921.862 us; speedup 1.0000x reference)
//
#include <hip/hip_runtime.h>

// LSTM decoder w/ Bahdanau attention, MI355X.
// Persistent grid-synchronized kernel, 256 blocks x 512 threads (1 block/CU).
//   keys = enc @ Wk^T precomputed by a separate tiled GEMM kernel.
//   Per step t (TWO grid barriers):
//     PA: stage h[ba]->LDS; q[ba]=h@Wq^T in-block (4x duplicated, L2-resident Wq);
//         out(t-1)[ba]=h@Wfc^T; energies tanh(q+keys_reg)*v; unnorm softmax;
//         ctx partial atomicAdd + den atomicAdd; zero next-step accumulators.
//     PB: gates = [x_t, ctx, h] @ [Wih|Whh]^T + bias; LSTM pointwise; h/c update.
//         Gate weights persistent in REGISTERS (68 fp32/thread).
// R1: __threadfence/acquire => buffer_wbl2/inv (L2 flush) => 65us barriers. Use RELAXED
//     agent-scope atomics (sc1) for ALL cross-block mutable data.
// R2: LDS stride-64 = 8-way bank conflict; lane k-chunks must map bank==lane.
// R3: still latency-bound (VALU 11%): 3 barriers x multi-line flag polls + sc1 RT chains
//     = ~50us/step. Fix: 2 barriers/step, single-counter barrier (1 line, tid0 polls),
//     keys resident in VGPRs (step-invariant!), memset-based init (no prologue zeroing).

#define B 64
#define T 128
#define IN_DIM 64
#define TE 256
#define HID 512
#define ATTN 256
#define OUTD 64
#define KIN 1088   // 64 (x) + 512 (ctx) + 512 (h)
#define G 256      // main grid blocks
#define BS 512     // main block threads

__device__ __forceinline__ float fast_exp(float x) {
  return __builtin_amdgcn_exp2f(x * 1.44269504f);
}
__device__ __forceinline__ float fast_tanh(float x) {
  float ax = fabsf(x);
  float z = __builtin_amdgcn_exp2f(ax * -2.885390082f);  // e^{-2|x|}
  float r = (1.f - z) * __builtin_amdgcn_rcpf(1.f + z);
  return copysignf(r, x);
}
__device__ __forceinline__ float fast_sig(float x) {
  float z = __builtin_amdgcn_exp2f(x * -1.44269504f);    // e^{-x}
  return __builtin_amdgcn_rcpf(1.f + z);
}

// Relaxed agent-scope atomics: global_load/store ... sc1 (coherence point, no L2 flush).
__device__ __forceinline__ float ald(const float* p) {
  return __hip_atomic_load((float*)p, __ATOMIC_RELAXED, __HIP_MEMORY_SCOPE_AGENT);
}
__device__ __forceinline__ void ast(float* p, float v) {
  __hip_atomic_store(p, v, __ATOMIC_RELAXED, __HIP_MEMORY_SCOPE_AGENT);
}

// Single-counter barrier: every wave drains VMEM (sc1 ops ack at coherence point),
// block joins, tid0 arrives via relaxed fetch_add and polls ONE cache line until
// cnt >= seq*G. cnt pre-zeroed by hipMemsetAsync before launch (re-done every call).
__device__ __forceinline__ void gridbar(int* cnt, int seq, int tid) {
  asm volatile("s_waitcnt vmcnt(0)" ::: "memory");
  __syncthreads();
  if (tid == 0) {
    __hip_atomic_fetch_add(cnt, 1, __ATOMIC_RELAXED, __HIP_MEMORY_SCOPE_AGENT);
    while (__hip_atomic_load(cnt, __ATOMIC_RELAXED, __HIP_MEMORY_SCOPE_AGENT) <
           seq * G) {
      __builtin_amdgcn_s_sleep(2);
    }
  }
  __syncthreads();
}

// ---- keys[b][e][a] = sum_k enc[b][e][k] * Wk[a][k] ----
__global__ __launch_bounds__(256, 2) void keys_kernel(
    const float* __restrict__ enc, const float* __restrict__ Wk,
    float* __restrict__ keys) {
  __shared__ float et[16][512];
  __shared__ float wk[32][256];
  const int tid = threadIdx.x;
  const int b = blockIdx.x >> 4;
  const int e0 = (blockIdx.x & 15) * 16;

  for (int p = 0; p < 8; ++p) {
    int i = p * 256 + tid;
    int e = i >> 7, kq = i & 127;
    float4 vv = *(const float4*)&enc[((size_t)(b * TE + e0 + e)) * HID + kq * 4];
    *(float4*)&et[e][kq * 4] = vv;
  }

  float acc[8][2];
  #pragma unroll
  for (int i = 0; i < 8; ++i) { acc[i][0] = 0.f; acc[i][1] = 0.f; }
  const int a0 = tid & 127;
  const int eh = (tid >> 7) * 8;

  for (int kc = 0; kc < 512; kc += 32) {
    __syncthreads();
    for (int p = 0; p < 8; ++p) {
      int i = p * 256 + tid;
      int a = i >> 3, j4 = (i & 7) * 4;
      float4 w4 = *(const float4*)&Wk[(size_t)a * HID + kc + j4];
      wk[j4 + 0][a] = w4.x; wk[j4 + 1][a] = w4.y;
      wk[j4 + 2][a] = w4.z; wk[j4 + 3][a] = w4.w;
    }
    __syncthreads();
    for (int k = 0; k < 32; ++k) {
      float w0 = wk[k][a0], w1 = wk[k][a0 + 128];
      #pragma unroll
      for (int i = 0; i < 8; ++i) {
        float ev = et[eh + i][kc + k];
        acc[i][0] = fmaf(ev, w0, acc[i][0]);
        acc[i][1] = fmaf(ev, w1, acc[i][1]);
      }
    }
  }
  #pragma unroll
  for (int i = 0; i < 8; ++i) {
    keys[((size_t)(b * TE + e0 + eh + i)) * ATTN + a0] = acc[i][0];
    keys[((size_t)(b * TE + e0 + eh + i)) * ATTN + a0 + 128] = acc[i][1];
  }
}

__global__ __launch_bounds__(BS, 2) void main_kernel(
    const float* __restrict__ x, const float* __restrict__ enc,
    const float* __restrict__ Wq, const float* __restrict__ v,
    const float* __restrict__ Wih, const float* __restrict__ Whh,
    const float* __restrict__ bih, const float* __restrict__ bhh,
    const float* __restrict__ Wfc, const float* __restrict__ bfc,
    const float* __restrict__ keys,
    float* hbuf, float* cbuf, float* ctxb, float* denb,
    int* cnt, float* out) {
  const int bid = blockIdx.x, tid = threadIdx.x;
  // PA role: ba = batch, s4 = enc-row quarter. PB role: rg = hid-slice, bg = batch group.
  const int ba = bid >> 2, s4 = bid & 3;
  const int rg = bid >> 2, bg = bid & 3;
  const int lane = tid & 63, wv = tid >> 6;
  const int r_loc = tid & 31, ks = tid >> 5;
  const int grow = (r_loc >> 3) * 512 + rg * 8 + (r_loc & 7);
  const int qr8 = tid >> 4;          // 0..31: owns q rows [qr8*8, +8)
  const int qk = tid & 15;           // k-chunk id (16 lanes/row, coalesced)

  __shared__ float ilds[16][KIN];           // 69.6 KB staged inputs (16 batch) [PB]
  __shared__ float parts[16][16][33];       // 33.8 KB dot partials [bb][ks][r]
  __shared__ float glds[16][32];            // gate values
  __shared__ float qlds[ATTN];              // PA: q vector for batch ba
  __shared__ float lw[64];                  // PA: exp weights
  __shared__ float blds[32];                // biases for this block's gate rows
  float* hlds = &ilds[0][0];                // [512] aliases ilds (barrier-separated)

  // ---- prologue: persistent registers (weights, keys, v, biases) ----
  float wreg[68];
  #pragma unroll
  for (int i = 0; i < 68; ++i) {
    const int k = ks * 68 + i;
    wreg[i] = (k < 576) ? Wih[(size_t)grow * 576 + k]
                        : Whh[(size_t)grow * 512 + (k - 576)];
  }
  if (tid < 32) {
    const int gr2 = (tid >> 3) * 512 + rg * 8 + (tid & 7);
    blds[tid] = bih[gr2] + bhh[gr2];
  }
  float vv4[4];
  #pragma unroll
  for (int j = 0; j < 4; ++j) vv4[j] = v[lane + 64 * j];
  // keys are STEP-INVARIANT per block: resident in VGPRs for the whole kernel
  float kk[8][4];
  #pragma unroll
  for (int i = 0; i < 8; ++i) {
    const float* krow = keys + ((size_t)(ba * TE) + s4 * 64 + wv * 8 + i) * ATTN;
    #pragma unroll
    for (int j = 0; j < 4; ++j) kk[i][j] = krow[lane + 64 * j];
  }

  int seq = 0;

  for (int t = 0; t < T; ++t) {
    // ================= PA: attention (+ q, + out(t-1)) =================
    {
      const float* hprev = hbuf + (size_t)(t & 1) * B * HID;
      hlds[tid] = ald(hprev + ba * HID + tid);
      __syncthreads();
      // q[r] = h . Wq[r]: 16 lanes per row, 32-float chunks, coalesced
      #pragma unroll
      for (int rr = 0; rr < 8; ++rr) {
        const int r = qr8 * 8 + rr;
        const float* wr = Wq + (size_t)r * HID;
        float acc = 0.f;
        #pragma unroll
        for (int i = 0; i < 8; ++i) {
          const int k = qk * 4 + 64 * i;
          float4 h4 = *(const float4*)&hlds[k];
          float4 w4 = *(const float4*)&wr[k];
          acc = fmaf(h4.x, w4.x, acc); acc = fmaf(h4.y, w4.y, acc);
          acc = fmaf(h4.z, w4.z, acc); acc = fmaf(h4.w, w4.w, acc);
        }
        acc += __shfl_xor(acc, 1, 64); acc += __shfl_xor(acc, 2, 64);
        acc += __shfl_xor(acc, 4, 64); acc += __shfl_xor(acc, 8, 64);
        if (qk == 0) qlds[r] = acc;
      }
      // out(t-1) for batch ba, slice s4*16..+16 (hlds still valid)
      if (t >= 1 && tid < 256) {
        const int oo = tid >> 4, og = s4 * 16 + oo;
        const float* wr = Wfc + (size_t)og * HID;
        float acc = 0.f;
        #pragma unroll
        for (int i = 0; i < 8; ++i) {
          const int k = qk * 4 + 64 * i;
          float4 h4 = *(const float4*)&hlds[k];
          float4 w4 = *(const float4*)&wr[k];
          acc = fmaf(h4.x, w4.x, acc); acc = fmaf(h4.y, w4.y, acc);
          acc = fmaf(h4.z, w4.z, acc); acc = fmaf(h4.w, w4.w, acc);
        }
        acc += __shfl_xor(acc, 1, 64); acc += __shfl_xor(acc, 2, 64);
        acc += __shfl_xor(acc, 4, 64); acc += __shfl_xor(acc, 8, 64);
        if (qk == 0)
          out[((size_t)ba * T + (t - 1)) * OUTD + og] = acc + bfc[og];
      }
      __syncthreads();
      // energies -> lw (keys from registers)
      float q4[4];
      #pragma unroll
      for (int j = 0; j < 4; ++j) q4[j] = qlds[lane + 64 * j];
      #pragma unroll
      for (int i = 0; i < 8; ++i) {
        float p = 0.f;
        #pragma unroll
        for (int j = 0; j < 4; ++j)
          p = fmaf(fast_tanh(q4[j] + kk[i][j]), vv4[j], p);
        #pragma unroll
        for (int m = 1; m < 64; m <<= 1) p += __shfl_xor(p, m, 64);
        if (lane == 0) lw[wv * 8 + i] = fast_exp(p);
      }
      __syncthreads();
      // denominator partial
      if (tid < 64) {
        float p = lw[tid];
        #pragma unroll
        for (int m = 1; m < 64; m <<= 1) p += __shfl_xor(p, m, 64);
        if (tid == 0) atomicAdd(denb + (t & 1) * B + ba, p);
      }
      // zero next step's accumulators (barrier-separated from readers/writers)
      if (tid < 128)
        ast(ctxb + (size_t)((t + 1) & 1) * B * HID + ba * HID + s4 * 128 + tid, 0.f);
      if (s4 == 0 && tid == 0) ast(denb + ((t + 1) & 1) * B + ba, 0.f);
      // context partial: 64 enc rows, col = tid, 4 indep accumulators
      const float* erow = enc + ((size_t)(ba * TE) + s4 * 64) * HID + tid;
      float a0 = 0.f, a1 = 0.f, a2 = 0.f, a3 = 0.f;
      #pragma unroll
      for (int e = 0; e < 64; e += 4) {
        a0 = fmaf(lw[e],     erow[(size_t)e * HID],       a0);
        a1 = fmaf(lw[e + 1], erow[(size_t)(e + 1) * HID], a1);
        a2 = fmaf(lw[e + 2], erow[(size_t)(e + 2) * HID], a2);
        a3 = fmaf(lw[e + 3], erow[(size_t)(e + 3) * HID], a3);
      }
      atomicAdd(ctxb + (size_t)(t & 1) * B * HID + ba * HID + tid,
                (a0 + a1) + (a2 + a3));
    }
    ++seq; gridbar(cnt, seq, tid);

    // ================= PB: gates + LSTM update =================
    {
      const float* hprev = hbuf + (size_t)(t & 1) * B * HID;
      float* hnext = hbuf + (size_t)((t + 1) & 1) * B * HID;
      const float* ctxcur = ctxb + (size_t)(t & 1) * B * HID;
      float li[16];
      #pragma unroll
      for (int j = 0; j < 16; ++j)
        li[j] = __builtin_amdgcn_rcpf(ald(denb + (t & 1) * B + bg * 16 + j));
      // stage all 16 batches in ONE latency window
      #pragma unroll
      for (int bb = 0; bb < 16; ++bb) {
        const int bglob = bg * 16 + bb;
        float va = (tid < 64) ? x[((size_t)bglob * T + t) * IN_DIM + tid]
                              : ald(ctxcur + bglob * HID + (tid - 64)) * li[bb];
        float vb = (tid < 64) ? ald(ctxcur + bglob * HID + (tid + 448)) * li[bb]
                              : ald(hprev + bglob * HID + (tid - 64));
        ilds[bb][tid] = va;
        ilds[bb][tid + 512] = vb;
        if (tid < 64) ilds[bb][tid + 1024] = ald(hprev + bglob * HID + (tid + 448));
      }
      __syncthreads();
      #pragma unroll
      for (int bb = 0; bb < 16; ++bb) {
        const float* ib = &ilds[bb][ks * 68];
        float a0 = 0.f;
        #pragma unroll
        for (int i = 0; i < 17; ++i) {
          float4 iv = ((const float4*)ib)[i];
          a0 = fmaf(wreg[4 * i + 0], iv.x, a0);
          a0 = fmaf(wreg[4 * i + 1], iv.y, a0);
          a0 = fmaf(wreg[4 * i + 2], iv.z, a0);
          a0 = fmaf(wreg[4 * i + 3], iv.w, a0);
        }
        parts[bb][ks][r_loc] = a0;
      }
      __syncthreads();
      {
        const int bbl = tid >> 5, rr = tid & 31;
        float s = blds[rr];
        #pragma unroll
        for (int j = 0; j < 16; ++j) s += parts[bbl][j][rr];
        glds[bbl][rr] = s;
      }
      __syncthreads();
      if (tid < 128) {
        const int bbl = tid >> 3, hl = tid & 7;
        const int b = bg * 16 + bbl, hu = rg * 8 + hl;
        const float gi = glds[bbl][hl],      gf = glds[bbl][8 + hl];
        const float gg = glds[bbl][16 + hl], go = glds[bbl][24 + hl];
        const float cold = cbuf[b * HID + hu];  // block-private: plain cached ok
        const float cn = fast_sig(gf) * cold + fast_sig(gi) * fast_tanh(gg);
        const float hn = fast_sig(go) * fast_tanh(cn);
        cbuf[b * HID + hu] = cn;
        ast(&hnext[b * HID + hu], hn);
      }
    }
    ++seq; gridbar(cnt, seq, tid);
  }

  // ---------------- epilogue: out(127) from h_127 (in hbuf[0]) ----------------
  {
    hlds[tid] = ald(hbuf + ba * HID + tid);  // (128 & 1) == 0
    __syncthreads();
    if (tid < 256) {
      const int oo = tid >> 4, og = s4 * 16 + oo;
      const float* wr = Wfc + (size_t)og * HID;
      float acc = 0.f;
      #pragma unroll
      for (int i = 0; i < 8; ++i) {
        const int k = qk * 4 + 64 * i;
        float4 h4 = *(const float4*)&hlds[k];
        float4 w4 = *(const float4*)&wr[k];
        acc = fmaf(h4.x, w4.x, acc); acc = fmaf(h4.y, w4.y, acc);
        acc = fmaf(h4.z, w4.z, acc); acc = fmaf(h4.w, w4.w, acc);
      }
      acc += __shfl_xor(acc, 1, 64); acc += __shfl_xor(acc, 2, 64);
      acc += __shfl_xor(acc, 4, 64); acc += __shfl_xor(acc, 8, 64);
      if (qk == 0)
        out[((size_t)ba * T + 127) * OUTD + og] = acc + bfc[og];
    }
  }
}

extern "C" void kernel_launch(void* const* d_in, const int* in_sizes, int n_in,
                              void* d_out, int out_size, void* d_ws, size_t ws_size,
                              hipStream_t stream) {
  const float* x   = (const float*)d_in[0];
  const float* enc = (const float*)d_in[1];
  const float* Wq  = (const float*)d_in[2];
  const float* Wk  = (const float*)d_in[3];
  const float* v   = (const float*)d_in[4];
  const float* Wih = (const float*)d_in[5];
  const float* Whh = (const float*)d_in[6];
  const float* bih = (const float*)d_in[7];
  const float* bhh = (const float*)d_in[8];
  const float* Wfc = (const float*)d_in[9];
  const float* bfc = (const float*)d_in[10];

  float* ws   = (float*)d_ws;                 // ~17.4 MB
  float* keys = ws;                           // B*TE*ATTN = 4194304 floats
  float* hbuf = keys + (size_t)B * TE * ATTN; // 2 buffers: 65536
  float* cbuf = hbuf + 2 * B * HID;           // 32768
  float* ctxb = cbuf + B * HID;               // 2 buffers: 65536
  float* denb = ctxb + 2 * B * HID;           // 2 buffers: 128
  int*   cnt  = (int*)(denb + 2 * B);         // barrier counter (own line)

  // zero all mutable cross-block state + barrier counter (stream-ordered,
  // graph-capturable; harness re-poisons ws before every timed call)
  const size_t mut_floats = 2 * B * HID + B * HID + 2 * B * HID + 2 * B + 16;
  hipMemsetAsync(hbuf, 0, mut_floats * sizeof(float), stream);

  keys_kernel<<<dim3(1024), dim3(256), 0, stream>>>(enc, Wk, keys);
  main_kernel<<<dim3(G), dim3(BS), 0, stream>>>(
      x, enc, Wq, v, Wih, Whh, bih, bhh, Wfc, bfc,
      keys, hbuf, cbuf, ctxb, denb, cnt, (float*)d_out);
}

// Round 5
// 8281.792 us; speedup vs baseline: 1.1980x; 1.1980x over previous
//
#include <hip/hip_runtime.h>

// LSTM decoder w/ Bahdanau attention, MI355X.
// Persistent grid-synchronized kernel, 256 blocks x 512 threads (1 block/CU).
// TWO grid barriers per step:
//   PA (block = (batch b, quarter qt)): stage h[b]->LDS; q[256]=h@Wq2^T in-block (bf16
//       weights, L2-resident); out(t-1)=h@Wfc2^T (qt==0); energies over 64 enc rows
//       (keys2 in VGPRs, step-invariant); UNNORMALIZED exp -> ctx partial + den partial
//       written with plain sc1 stores (softmax partials are linear => NO atomics, NO
//       zeroing, NO cross-block softmax exchange).
//   PB (block = (row-slice rg, batch-group bg)): gates = [x,ctx,h]@[Wih|Whh]^T + bias,
//       weights persistent in REGISTERS (68 fp32/thread); ctx = (sum of 4 quarter
//       partials) * rcp(sum of 4 den partials); LSTM pointwise; h/c update.
// R1: __threadfence/acquire => buffer_wbl2/inv per op => 65us barriers. Use RELAXED
//     agent-scope (sc1) atomics for all cross-block mutable data.
// R2: LDS chunk strides ≡ 0 mod 32 banks => 8-way conflicts; map bank==lane or rotate.
// R3: multi-line flag barrier OK (no outliers); 1-flag-per-lane polling here.
// R4: single-counter barrier collapses under 256 spinners (40ms outliers); redundant
//     fp32 Wq thrashes L2 (FETCH 2x, serial L3 latency). Fix: bf16 read-only operands
//     (working set < L2), flag-array barrier.

#define B 64
#define T 128
#define IN_DIM 64
#define TE 256
#define HID 512
#define ATTN 256
#define OUTD 64
#define KIN 1088   // 64 (x) + 512 (ctx) + 512 (h)
#define G 256
#define BS 512

__device__ __forceinline__ float fast_exp(float x) {
  return __builtin_amdgcn_exp2f(x * 1.44269504f);
}
__device__ __forceinline__ float fast_tanh(float x) {
  float ax = fabsf(x);
  float z = __builtin_amdgcn_exp2f(ax * -2.885390082f);  // e^{-2|x|}
  float r = (1.f - z) * __builtin_amdgcn_rcpf(1.f + z);
  return copysignf(r, x);
}
__device__ __forceinline__ float fast_sig(float x) {
  float z = __builtin_amdgcn_exp2f(x * -1.44269504f);    // e^{-x}
  return __builtin_amdgcn_rcpf(1.f + z);
}
// bf16 (stored as ushort) -> float
__device__ __forceinline__ float bfu(unsigned short u) {
  return __uint_as_float((unsigned)u << 16);
}
__device__ __forceinline__ float bflo(unsigned u) { return __uint_as_float(u << 16); }
__device__ __forceinline__ float bfhi(unsigned u) {
  return __uint_as_float(u & 0xffff0000u);
}

// Relaxed agent-scope atomics: global_load/store ... sc1 (coherence point, no L2 flush).
__device__ __forceinline__ float ald(const float* p) {
  return __hip_atomic_load((float*)p, __ATOMIC_RELAXED, __HIP_MEMORY_SCOPE_AGENT);
}
__device__ __forceinline__ void ast(float* p, float v) {
  __hip_atomic_store(p, v, __ATOMIC_RELAXED, __HIP_MEMORY_SCOPE_AGENT);
}

// Flag-array barrier: each wave drains its VMEM (sc1 ops ack at coherence point),
// block joins, tid0 publishes, tids 0..255 poll ONE flag each (4 lines total).
// Signed >= compare: 0xAA poison is negative as int32 -> never false-passes.
__device__ __forceinline__ void gridbar(int* flags, int seq, int bid, int tid) {
  asm volatile("s_waitcnt vmcnt(0)" ::: "memory");
  __syncthreads();
  if (tid == 0)
    __hip_atomic_store(&flags[bid], seq, __ATOMIC_RELAXED, __HIP_MEMORY_SCOPE_AGENT);
  if (tid < G) {
    while (__hip_atomic_load(&flags[tid], __ATOMIC_RELAXED,
                             __HIP_MEMORY_SCOPE_AGENT) < seq) {
      __builtin_amdgcn_s_sleep(1);
    }
  }
  __syncthreads();
}

// fp32 -> bf16 (RNE)
__global__ void cvt_kernel(const float* __restrict__ src, unsigned short* __restrict__ dst,
                           int n) {
  for (int i = blockIdx.x * blockDim.x + threadIdx.x; i < n;
       i += gridDim.x * blockDim.x) {
    unsigned u = __float_as_uint(src[i]);
    dst[i] = (unsigned short)((u + 0x7fff + ((u >> 16) & 1)) >> 16);
  }
}

// ---- keys2[b][e][a] = bf16( sum_k enc[b][e][k] * Wk[a][k] ) ----
__global__ __launch_bounds__(256, 2) void keys_kernel(
    const float* __restrict__ enc, const float* __restrict__ Wk,
    unsigned short* __restrict__ keys2) {
  __shared__ float et[16][512];
  __shared__ float wk[32][256];
  const int tid = threadIdx.x;
  const int b = blockIdx.x >> 4;
  const int e0 = (blockIdx.x & 15) * 16;

  for (int p = 0; p < 8; ++p) {
    int i = p * 256 + tid;
    int e = i >> 7, kq = i & 127;
    float4 vv = *(const float4*)&enc[((size_t)(b * TE + e0 + e)) * HID + kq * 4];
    *(float4*)&et[e][kq * 4] = vv;
  }

  float acc[8][2];
  #pragma unroll
  for (int i = 0; i < 8; ++i) { acc[i][0] = 0.f; acc[i][1] = 0.f; }
  const int a0 = tid & 127;
  const int eh = (tid >> 7) * 8;

  for (int kc = 0; kc < 512; kc += 32) {
    __syncthreads();
    for (int p = 0; p < 8; ++p) {
      int i = p * 256 + tid;
      int a = i >> 3, j4 = (i & 7) * 4;
      float4 w4 = *(const float4*)&Wk[(size_t)a * HID + kc + j4];
      wk[j4 + 0][a] = w4.x; wk[j4 + 1][a] = w4.y;
      wk[j4 + 2][a] = w4.z; wk[j4 + 3][a] = w4.w;
    }
    __syncthreads();
    for (int k = 0; k < 32; ++k) {
      float w0 = wk[k][a0], w1 = wk[k][a0 + 128];
      #pragma unroll
      for (int i = 0; i < 8; ++i) {
        float ev = et[eh + i][kc + k];
        acc[i][0] = fmaf(ev, w0, acc[i][0]);
        acc[i][1] = fmaf(ev, w1, acc[i][1]);
      }
    }
  }
  #pragma unroll
  for (int i = 0; i < 8; ++i) {
    #pragma unroll
    for (int h = 0; h < 2; ++h) {
      unsigned u = __float_as_uint(acc[i][h]);
      keys2[((size_t)(b * TE + e0 + eh + i)) * ATTN + a0 + 128 * h] =
          (unsigned short)((u + 0x7fff + ((u >> 16) & 1)) >> 16);
    }
  }
}

__global__ __launch_bounds__(BS, 2) void main_kernel(
    const float* __restrict__ x, const float* __restrict__ v,
    const float* __restrict__ Wih, const float* __restrict__ Whh,
    const float* __restrict__ bih, const float* __restrict__ bhh,
    const float* __restrict__ bfc,
    const unsigned short* __restrict__ enc2, const unsigned short* __restrict__ keys2,
    const unsigned short* __restrict__ Wq2, const unsigned short* __restrict__ Wfc2,
    float* hbuf, float* cbuf, float* ctxq, float* denq,
    int* flags, float* out) {
  const int bid = blockIdx.x, tid = threadIdx.x;
  // PA role: batch b, enc-row quarter qt. PB role: hid-slice rg, batch group bg.
  const int b = bid >> 2, qt = bid & 3;
  const int rg = bid >> 2, bg = bid & 3;
  const int lane = tid & 63, wv = tid >> 6;
  const int r_loc = tid & 31, ks = tid >> 5;
  const int grow = (r_loc >> 3) * 512 + rg * 8 + (r_loc & 7);

  __shared__ float ilds[16][KIN];       // 69.6 KB staged inputs [PB]
  __shared__ float parts[16][16][33];   // 33.8 KB dot partials [PB]
  __shared__ float glds[16][32];        // gate values [PB]
  __shared__ float hsh[HID];            // PA: staged h[b]
  __shared__ float qsh[ATTN];           // PA: q vector
  __shared__ float lwsh[64];            // PA: exp weights (this quarter's rows)
  __shared__ float dsh[64];             // PB: den partials [qt][bb]
  __shared__ float blds[32];            // PB: biases

  // ---- prologue: persistent registers ----
  float wreg[68];
  #pragma unroll
  for (int i = 0; i < 68; ++i) {
    const int k = ks * 68 + i;
    wreg[i] = (k < 576) ? Wih[(size_t)grow * 576 + k]
                        : Whh[(size_t)grow * 512 + (k - 576)];
  }
  if (tid < 32) {
    const int gr2 = (tid >> 3) * 512 + rg * 8 + (tid & 7);
    blds[tid] = bih[gr2] + bhh[gr2];
  }
  const float4 vvf = *(const float4*)&v[lane * 4];   // a-chunk = lane*4..+4
  // keys2 rows for this block are STEP-INVARIANT: hold in VGPRs (as float)
  float kkf[8][4];
  #pragma unroll
  for (int i = 0; i < 8; ++i) {
    const unsigned short* kr =
        keys2 + ((size_t)(b * TE) + qt * 64 + wv * 8 + i) * ATTN + lane * 4;
    uint2 k4 = *(const uint2*)kr;
    kkf[i][0] = bflo(k4.x); kkf[i][1] = bfhi(k4.x);
    kkf[i][2] = bflo(k4.y); kkf[i][3] = bfhi(k4.y);
  }

  int seq = 0;

  for (int t = 0; t < T; ++t) {
    // ================= PA: attention in-block =================
    {
      const float* hprev = hbuf + (size_t)(t & 1) * B * HID;
      hsh[tid] = ald(hprev + (size_t)b * HID + tid);
      __syncthreads();
      // out(t-1) (qt==0): rows o=tid>>3, k-chunks c=tid&7, rotated (bank-conflict-free)
      if (qt == 0 && t >= 1) {
        const int o = tid >> 3, c = tid & 7;
        const unsigned short* wr = Wfc2 + (size_t)o * HID;
        float oa = 0.f;
        #pragma unroll
        for (int j = 0; j < 8; ++j) {
          const int jj = c * 64 + ((j + c) & 7) * 8;
          uint4 w8 = *(const uint4*)(wr + jj);
          const float* hp = &hsh[jj];
          oa = fmaf(bflo(w8.x), hp[0], oa); oa = fmaf(bfhi(w8.x), hp[1], oa);
          oa = fmaf(bflo(w8.y), hp[2], oa); oa = fmaf(bfhi(w8.y), hp[3], oa);
          oa = fmaf(bflo(w8.z), hp[4], oa); oa = fmaf(bfhi(w8.z), hp[5], oa);
          oa = fmaf(bflo(w8.w), hp[6], oa); oa = fmaf(bfhi(w8.w), hp[7], oa);
        }
        oa += __shfl_xor(oa, 1, 64); oa += __shfl_xor(oa, 2, 64);
        oa += __shfl_xor(oa, 4, 64);
        if (c == 0) out[((size_t)b * T + (t - 1)) * OUTD + o] = oa + bfc[o];
      }
      // q[256] = h @ Wq2^T: 2 threads/row, 256-elem halves (LDS reads broadcast)
      {
        const int r = tid >> 1, c2 = tid & 1;
        const unsigned short* wr = Wq2 + (size_t)r * HID + c2 * 256;
        const float* hb = &hsh[c2 * 256];
        float qa = 0.f;
        #pragma unroll 8
        for (int j = 0; j < 32; ++j) {
          uint4 w8 = ((const uint4*)wr)[j];
          const float* hp = hb + j * 8;
          qa = fmaf(bflo(w8.x), hp[0], qa); qa = fmaf(bfhi(w8.x), hp[1], qa);
          qa = fmaf(bflo(w8.y), hp[2], qa); qa = fmaf(bfhi(w8.y), hp[3], qa);
          qa = fmaf(bflo(w8.z), hp[4], qa); qa = fmaf(bfhi(w8.z), hp[5], qa);
          qa = fmaf(bflo(w8.w), hp[6], qa); qa = fmaf(bfhi(w8.w), hp[7], qa);
        }
        qa += __shfl_xor(qa, 1, 64);
        if (c2 == 0) qsh[r] = qa;
      }
      __syncthreads();
      // energies for this quarter's 64 rows (keys from VGPRs)
      {
        const float4 q4 = *(const float4*)&qsh[lane * 4];
        #pragma unroll
        for (int i = 0; i < 8; ++i) {
          float p = fast_tanh(q4.x + kkf[i][0]) * vvf.x;
          p = fmaf(fast_tanh(q4.y + kkf[i][1]), vvf.y, p);
          p = fmaf(fast_tanh(q4.z + kkf[i][2]), vvf.z, p);
          p = fmaf(fast_tanh(q4.w + kkf[i][3]), vvf.w, p);
          #pragma unroll
          for (int m = 1; m < 64; m <<= 1) p += __shfl_xor(p, m, 64);
          if (lane == 0) lwsh[wv * 8 + i] = fast_exp(p);
        }
      }
      __syncthreads();
      // den partial (plain sc1 store, no atomic)
      if (tid < 64) {
        float p = lwsh[tid];
        #pragma unroll
        for (int m = 1; m < 64; m <<= 1) p += __shfl_xor(p, m, 64);
        if (tid == 0) ast(denq + qt * B + b, p);
      }
      // ctx partial over 64 enc2 rows, col d = tid (unnormalized)
      {
        const unsigned short* erow = enc2 + ((size_t)(b * TE) + qt * 64) * HID + tid;
        float a0 = 0.f, a1 = 0.f, a2 = 0.f, a3 = 0.f;
        #pragma unroll
        for (int e = 0; e < 64; e += 4) {
          a0 = fmaf(lwsh[e],     bfu(erow[(size_t)e * HID]),       a0);
          a1 = fmaf(lwsh[e + 1], bfu(erow[(size_t)(e + 1) * HID]), a1);
          a2 = fmaf(lwsh[e + 2], bfu(erow[(size_t)(e + 2) * HID]), a2);
          a3 = fmaf(lwsh[e + 3], bfu(erow[(size_t)(e + 3) * HID]), a3);
        }
        ast(ctxq + ((size_t)qt * B + b) * HID + tid, (a0 + a1) + (a2 + a3));
      }
    }
    ++seq; gridbar(flags, seq, bid, tid);

    // ================= PB: gates + LSTM update =================
    {
      const float* hprev = hbuf + (size_t)(t & 1) * B * HID;
      float* hnext = hbuf + (size_t)((t + 1) & 1) * B * HID;
      if (tid < 64)
        dsh[tid] = ald(denq + (tid >> 4) * B + bg * 16 + (tid & 15));
      __syncthreads();
      #pragma unroll
      for (int bb = 0; bb < 16; ++bb) {
        const int bgl = bg * 16 + bb;
        const float li = __builtin_amdgcn_rcpf(
            (dsh[bb] + dsh[16 + bb]) + (dsh[32 + bb] + dsh[48 + bb]));
        float va, vb;
        if (tid < 64) {
          va = x[((size_t)bgl * T + t) * IN_DIM + tid];
          const int d = tid + 448;
          vb = (ald(ctxq + (size_t)bgl * HID + d) +
                ald(ctxq + ((size_t)B + bgl) * HID + d) +
                ald(ctxq + ((size_t)2 * B + bgl) * HID + d) +
                ald(ctxq + ((size_t)3 * B + bgl) * HID + d)) * li;
          ilds[bb][tid + 1024] = ald(hprev + (size_t)bgl * HID + tid + 448);
        } else {
          const int d = tid - 64;
          va = (ald(ctxq + (size_t)bgl * HID + d) +
                ald(ctxq + ((size_t)B + bgl) * HID + d) +
                ald(ctxq + ((size_t)2 * B + bgl) * HID + d) +
                ald(ctxq + ((size_t)3 * B + bgl) * HID + d)) * li;
          vb = ald(hprev + (size_t)bgl * HID + d);
        }
        ilds[bb][tid] = va;
        ilds[bb][tid + 512] = vb;
      }
      __syncthreads();
      #pragma unroll
      for (int bb = 0; bb < 16; ++bb) {
        const float* ib = &ilds[bb][ks * 68];
        float a0 = 0.f;
        #pragma unroll
        for (int i = 0; i < 17; ++i) {
          float4 iv = ((const float4*)ib)[i];
          a0 = fmaf(wreg[4 * i + 0], iv.x, a0);
          a0 = fmaf(wreg[4 * i + 1], iv.y, a0);
          a0 = fmaf(wreg[4 * i + 2], iv.z, a0);
          a0 = fmaf(wreg[4 * i + 3], iv.w, a0);
        }
        parts[bb][ks][r_loc] = a0;
      }
      __syncthreads();
      {
        const int bbl = tid >> 5, rr = tid & 31;
        float s = blds[rr];
        #pragma unroll
        for (int j = 0; j < 16; ++j) s += parts[bbl][j][rr];
        glds[bbl][rr] = s;
      }
      __syncthreads();
      if (tid < 128) {
        const int bbl = tid >> 3, hl = tid & 7;
        const int bb2 = bg * 16 + bbl, hu = rg * 8 + hl;
        const float gi = glds[bbl][hl],      gf = glds[bbl][8 + hl];
        const float gg = glds[bbl][16 + hl], go = glds[bbl][24 + hl];
        const float cold = cbuf[bb2 * HID + hu];  // block-private: plain cached ok
        const float cn = fast_sig(gf) * cold + fast_sig(gi) * fast_tanh(gg);
        const float hn = fast_sig(go) * fast_tanh(cn);
        cbuf[bb2 * HID + hu] = cn;
        ast(&hnext[bb2 * HID + hu], hn);
      }
    }
    ++seq; gridbar(flags, seq, bid, tid);
  }

  // ---------------- epilogue: out(127) from h_128 (hbuf slot 0) ----------------
  if (qt == 0) {
    hsh[tid] = ald(hbuf + (size_t)b * HID + tid);
    __syncthreads();
    const int o = tid >> 3, c = tid & 7;
    const unsigned short* wr = Wfc2 + (size_t)o * HID;
    float oa = 0.f;
    #pragma unroll
    for (int j = 0; j < 8; ++j) {
      const int jj = c * 64 + ((j + c) & 7) * 8;
      uint4 w8 = *(const uint4*)(wr + jj);
      const float* hp = &hsh[jj];
      oa = fmaf(bflo(w8.x), hp[0], oa); oa = fmaf(bfhi(w8.x), hp[1], oa);
      oa = fmaf(bflo(w8.y), hp[2], oa); oa = fmaf(bfhi(w8.y), hp[3], oa);
      oa = fmaf(bflo(w8.z), hp[4], oa); oa = fmaf(bfhi(w8.z), hp[5], oa);
      oa = fmaf(bflo(w8.w), hp[6], oa); oa = fmaf(bfhi(w8.w), hp[7], oa);
    }
    oa += __shfl_xor(oa, 1, 64); oa += __shfl_xor(oa, 2, 64);
    oa += __shfl_xor(oa, 4, 64);
    if (c == 0) out[((size_t)b * T + 127) * OUTD + o] = oa + bfc[o];
  }
}

extern "C" void kernel_launch(void* const* d_in, const int* in_sizes, int n_in,
                              void* d_out, int out_size, void* d_ws, size_t ws_size,
                              hipStream_t stream) {
  const float* x   = (const float*)d_in[0];
  const float* enc = (const float*)d_in[1];
  const float* Wq  = (const float*)d_in[2];
  const float* Wk  = (const float*)d_in[3];
  const float* v   = (const float*)d_in[4];
  const float* Wih = (const float*)d_in[5];
  const float* Whh = (const float*)d_in[6];
  const float* bih = (const float*)d_in[7];
  const float* bhh = (const float*)d_in[8];
  const float* Wfc = (const float*)d_in[9];
  const float* bfc = (const float*)d_in[10];

  // ws layout (~26.5 MB)
  unsigned short* enc2  = (unsigned short*)d_ws;        // 8388608 bf16
  unsigned short* keys2 = enc2 + (size_t)B * TE * HID;  // 4194304 bf16
  unsigned short* Wq2   = keys2 + (size_t)B * TE * ATTN;  // 131072
  unsigned short* Wfc2  = Wq2 + ATTN * HID;               // 32768
  float* hbuf = (float*)(Wfc2 + OUTD * HID);  // 2 * B*HID
  float* cbuf = hbuf + 2 * B * HID;           // B*HID
  int*   flags = (int*)(cbuf + B * HID);      // 256
  float* ctxq = (float*)(flags + 256);        // 4 * B*HID (quarter partials)
  float* denq = ctxq + 4 * B * HID;           // 4 * B

  // zero h, c, flags in one stream-ordered memset (re-done every call)
  hipMemsetAsync(hbuf, 0, (3 * B * HID) * sizeof(float) + 256 * sizeof(int), stream);

  cvt_kernel<<<dim3(512), dim3(256), 0, stream>>>(enc, enc2, B * TE * HID);
  cvt_kernel<<<dim3(64), dim3(256), 0, stream>>>(Wq, Wq2, ATTN * HID);
  cvt_kernel<<<dim3(32), dim3(256), 0, stream>>>(Wfc, Wfc2, OUTD * HID);
  keys_kernel<<<dim3(1024), dim3(256), 0, stream>>>(enc, Wk, keys2);
  main_kernel<<<dim3(G), dim3(BS), 0, stream>>>(
      x, v, Wih, Whh, bih, bhh, bfc, enc2, keys2, Wq2, Wfc2,
      hbuf, cbuf, ctxq, denq, flags, (float*)d_out);
}

// Round 6
// 5739.923 us; speedup vs baseline: 1.7286x; 1.4428x over previous
//
#include <hip/hip_runtime.h>

// LSTM decoder w/ Bahdanau attention, MI355X.
// Persistent grid-synchronized kernel, 256 blocks x 512 threads (1 block/CU).
// TWO grid barriers per step:
//   PA (block=(batch b, quarter qt)): stage h[b](fp32)->LDS; q=h@Wq2^T in-block (bf16,
//       L2-resident); out(t-1)=h@Wfc2^T (qt==0); energies tanh(q+keys2_reg)*v;
//       unnormalized exp -> den atomicAdd + ctx atomicAdd (fp32, zero-ahead dbuf).
//   PB (block=(row-slice rg, batch-group bg)): stage [x(plain fp32) | ctx(sc1 fp32
//       * rcp(den)) | h(sc1 packed bf16)] -> LDS; gates GEMM with weights in REGISTERS
//       (68 fp32/thread); LSTM pointwise; h -> hbuf fp32 (for PA) + hpk bf16 (for PB).
// Lessons:
// R1: __threadfence/acquire => buffer_wbl2/inv per op => 65us barriers. RELAXED
//     agent-scope (sc1) atomics for all cross-block mutable data.
// R2: LDS strides ≡ 0 mod 32 banks => 8-way conflicts (incl. qsh[lane*4] b128!).
// R4: single-counter barrier collapses (256 spinners); fp32 Wq per-block thrashes L2.
// R5: THE WALL WAS NEVER BARRIERS: PB staged 43MB/step of L2-bypassing sc1 reads
//     (64x duplication x 4 ctx quarters). Fix: ctx pre-summed via atomicAdd, h as
//     packed bf16, x via plain cached loads => 12.3MB/step.

#define B 64
#define T 128
#define IN_DIM 64
#define TE 256
#define HID 512
#define ATTN 256
#define OUTD 64
#define KIN 1088   // 64 (x) + 512 (ctx) + 512 (h)
#define G 256
#define BS 512

__device__ __forceinline__ float fast_exp(float x) {
  return __builtin_amdgcn_exp2f(x * 1.44269504f);
}
__device__ __forceinline__ float fast_tanh(float x) {
  float ax = fabsf(x);
  float z = __builtin_amdgcn_exp2f(ax * -2.885390082f);  // e^{-2|x|}
  float r = (1.f - z) * __builtin_amdgcn_rcpf(1.f + z);
  return copysignf(r, x);
}
__device__ __forceinline__ float fast_sig(float x) {
  float z = __builtin_amdgcn_exp2f(x * -1.44269504f);    // e^{-x}
  return __builtin_amdgcn_rcpf(1.f + z);
}
__device__ __forceinline__ float bfu(unsigned short u) {
  return __uint_as_float((unsigned)u << 16);
}
__device__ __forceinline__ float bflo(unsigned u) { return __uint_as_float(u << 16); }
__device__ __forceinline__ float bfhi(unsigned u) {
  return __uint_as_float(u & 0xffff0000u);
}
__device__ __forceinline__ unsigned f2bf(float f) {  // RNE bf16 bits
  unsigned u = __float_as_uint(f);
  return (u + 0x7fff + ((u >> 16) & 1)) >> 16;
}

// Relaxed agent-scope atomics: global_load/store ... sc1 (coherence point, no L2 flush).
__device__ __forceinline__ float ald(const float* p) {
  return __hip_atomic_load((float*)p, __ATOMIC_RELAXED, __HIP_MEMORY_SCOPE_AGENT);
}
__device__ __forceinline__ float2 ald2(const float* p) {
  double d = __hip_atomic_load((const double*)p, __ATOMIC_RELAXED,
                               __HIP_MEMORY_SCOPE_AGENT);
  union { double d; float2 f; } u; u.d = d; return u.f;
}
__device__ __forceinline__ unsigned aldu(const unsigned* p) {
  return __hip_atomic_load(p, __ATOMIC_RELAXED, __HIP_MEMORY_SCOPE_AGENT);
}
__device__ __forceinline__ void ast(float* p, float v) {
  __hip_atomic_store(p, v, __ATOMIC_RELAXED, __HIP_MEMORY_SCOPE_AGENT);
}
__device__ __forceinline__ void astu(unsigned* p, unsigned v) {
  __hip_atomic_store(p, v, __ATOMIC_RELAXED, __HIP_MEMORY_SCOPE_AGENT);
}

// Flag-array barrier (R3/R5-proven, no outliers). Signed >= : 0xAA poison is negative.
__device__ __forceinline__ void gridbar(int* flags, int seq, int bid, int tid) {
  asm volatile("s_waitcnt vmcnt(0)" ::: "memory");
  __syncthreads();
  if (tid == 0)
    __hip_atomic_store(&flags[bid], seq, __ATOMIC_RELAXED, __HIP_MEMORY_SCOPE_AGENT);
  if (tid < G) {
    while (__hip_atomic_load(&flags[tid], __ATOMIC_RELAXED,
                             __HIP_MEMORY_SCOPE_AGENT) < seq) {
      __builtin_amdgcn_s_sleep(1);
    }
  }
  __syncthreads();
}

// fp32 -> bf16 (RNE)
__global__ void cvt_kernel(const float* __restrict__ src,
                           unsigned short* __restrict__ dst, int n) {
  for (int i = blockIdx.x * blockDim.x + threadIdx.x; i < n;
       i += gridDim.x * blockDim.x)
    dst[i] = (unsigned short)f2bf(src[i]);
}

// ---- keys2[b][e][a] = bf16( sum_k enc[b][e][k] * Wk[a][k] ) ----
__global__ __launch_bounds__(256, 2) void keys_kernel(
    const float* __restrict__ enc, const float* __restrict__ Wk,
    unsigned short* __restrict__ keys2) {
  __shared__ float et[16][512];
  __shared__ float wk[32][256];
  const int tid = threadIdx.x;
  const int b = blockIdx.x >> 4;
  const int e0 = (blockIdx.x & 15) * 16;

  for (int p = 0; p < 8; ++p) {
    int i = p * 256 + tid;
    int e = i >> 7, kq = i & 127;
    float4 vv = *(const float4*)&enc[((size_t)(b * TE + e0 + e)) * HID + kq * 4];
    *(float4*)&et[e][kq * 4] = vv;
  }

  float acc[8][2];
  #pragma unroll
  for (int i = 0; i < 8; ++i) { acc[i][0] = 0.f; acc[i][1] = 0.f; }
  const int a0 = tid & 127;
  const int eh = (tid >> 7) * 8;

  for (int kc = 0; kc < 512; kc += 32) {
    __syncthreads();
    for (int p = 0; p < 8; ++p) {
      int i = p * 256 + tid;
      int a = i >> 3, j4 = (i & 7) * 4;
      float4 w4 = *(const float4*)&Wk[(size_t)a * HID + kc + j4];
      wk[j4 + 0][a] = w4.x; wk[j4 + 1][a] = w4.y;
      wk[j4 + 2][a] = w4.z; wk[j4 + 3][a] = w4.w;
    }
    __syncthreads();
    for (int k = 0; k < 32; ++k) {
      float w0 = wk[k][a0], w1 = wk[k][a0 + 128];
      #pragma unroll
      for (int i = 0; i < 8; ++i) {
        float ev = et[eh + i][kc + k];
        acc[i][0] = fmaf(ev, w0, acc[i][0]);
        acc[i][1] = fmaf(ev, w1, acc[i][1]);
      }
    }
  }
  #pragma unroll
  for (int i = 0; i < 8; ++i)
    #pragma unroll
    for (int h = 0; h < 2; ++h)
      keys2[((size_t)(b * TE + e0 + eh + i)) * ATTN + a0 + 128 * h] =
          (unsigned short)f2bf(acc[i][h]);
}

__global__ __launch_bounds__(BS, 2) void main_kernel(
    const float* __restrict__ x, const float* __restrict__ v,
    const float* __restrict__ Wih, const float* __restrict__ Whh,
    const float* __restrict__ bih, const float* __restrict__ bhh,
    const float* __restrict__ bfc,
    const unsigned short* __restrict__ enc2, const unsigned short* __restrict__ keys2,
    const unsigned short* __restrict__ Wq2, const unsigned short* __restrict__ Wfc2,
    float* hbuf, float* cbuf, float* ctxb, float* denb, unsigned* hpk,
    int* flags, float* out) {
  const int bid = blockIdx.x, tid = threadIdx.x;
  const int b = bid >> 2, qt = bid & 3;        // PA role
  const int rg = bid >> 2, bg = bid & 3;       // PB role
  const int lane = tid & 63, wv = tid >> 6;
  const int r_loc = tid & 31, ks = tid >> 5;
  const int grow = (r_loc >> 3) * 512 + rg * 8 + (r_loc & 7);

  __shared__ float ilds[16][KIN];       // 69.6 KB staged inputs [PB]
  __shared__ float parts[16][16][33];   // 33.8 KB dot partials [PB]
  __shared__ float glds[16][32];        // gate values [PB]
  __shared__ float hsh[HID];            // PA: staged h[b] (fp32)
  __shared__ float qsh[320];            // PA: q, swizzled idx r+(r>>2) (conflict-free)
  __shared__ float lwsh[64];            // PA: exp weights (this quarter's rows)
  __shared__ float dsh[16];             // PB: den per batch in group
  __shared__ float blds[32];            // PB: biases

  // ---- prologue: persistent registers ----
  float wreg[68];
  #pragma unroll
  for (int i = 0; i < 68; ++i) {
    const int k = ks * 68 + i;
    wreg[i] = (k < 576) ? Wih[(size_t)grow * 576 + k]
                        : Whh[(size_t)grow * 512 + (k - 576)];
  }
  if (tid < 32) {
    const int gr2 = (tid >> 3) * 512 + rg * 8 + (tid & 7);
    blds[tid] = bih[gr2] + bhh[gr2];
  }
  const float4 vvf = *(const float4*)&v[lane * 4];
  float kkf[8][4];  // step-invariant keys in VGPRs
  #pragma unroll
  for (int i = 0; i < 8; ++i) {
    const unsigned short* kr =
        keys2 + ((size_t)(b * TE) + qt * 64 + wv * 8 + i) * ATTN + lane * 4;
    uint2 k4 = *(const uint2*)kr;
    kkf[i][0] = bflo(k4.x); kkf[i][1] = bfhi(k4.x);
    kkf[i][2] = bflo(k4.y); kkf[i][3] = bfhi(k4.y);
  }

  int seq = 0;

  for (int t = 0; t < T; ++t) {
    // ================= PA: attention in-block =================
    {
      const float* hprev = hbuf + (size_t)(t & 1) * B * HID;
      hsh[tid] = ald(hprev + (size_t)b * HID + tid);
      __syncthreads();
      // out(t-1) (qt==0 only): rotated k-chunks, conflict-free
      if (qt == 0 && t >= 1) {
        const int o = tid >> 3, c = tid & 7;
        const unsigned short* wr = Wfc2 + (size_t)o * HID;
        float oa = 0.f;
        #pragma unroll
        for (int j = 0; j < 8; ++j) {
          const int jj = c * 64 + ((j + c) & 7) * 8;
          uint4 w8 = *(const uint4*)(wr + jj);
          const float* hp = &hsh[jj];
          oa = fmaf(bflo(w8.x), hp[0], oa); oa = fmaf(bfhi(w8.x), hp[1], oa);
          oa = fmaf(bflo(w8.y), hp[2], oa); oa = fmaf(bfhi(w8.y), hp[3], oa);
          oa = fmaf(bflo(w8.z), hp[4], oa); oa = fmaf(bfhi(w8.z), hp[5], oa);
          oa = fmaf(bflo(w8.w), hp[6], oa); oa = fmaf(bfhi(w8.w), hp[7], oa);
        }
        oa += __shfl_xor(oa, 1, 64); oa += __shfl_xor(oa, 2, 64);
        oa += __shfl_xor(oa, 4, 64);
        if (c == 0) out[((size_t)b * T + (t - 1)) * OUTD + o] = oa + bfc[o];
      }
      // q[256] = h @ Wq2^T: 2 threads/row (LDS broadcast reads)
      {
        const int r = tid >> 1, c2 = tid & 1;
        const unsigned short* wr = Wq2 + (size_t)r * HID + c2 * 256;
        const float* hb = &hsh[c2 * 256];
        float qa = 0.f;
        #pragma unroll 8
        for (int j = 0; j < 32; ++j) {
          uint4 w8 = ((const uint4*)wr)[j];
          const float* hp = hb + j * 8;
          qa = fmaf(bflo(w8.x), hp[0], qa); qa = fmaf(bfhi(w8.x), hp[1], qa);
          qa = fmaf(bflo(w8.y), hp[2], qa); qa = fmaf(bfhi(w8.y), hp[3], qa);
          qa = fmaf(bflo(w8.z), hp[4], qa); qa = fmaf(bfhi(w8.z), hp[5], qa);
          qa = fmaf(bflo(w8.w), hp[6], qa); qa = fmaf(bfhi(w8.w), hp[7], qa);
        }
        qa += __shfl_xor(qa, 1, 64);
        if (c2 == 0) qsh[r + (r >> 2)] = qa;  // swizzled store
      }
      __syncthreads();
      // energies (q read swizzled: idx(4*lane+j) = 5*lane+j -> conflict-free)
      {
        float q4[4];
        #pragma unroll
        for (int j = 0; j < 4; ++j) q4[j] = qsh[5 * lane + j];
        #pragma unroll
        for (int i = 0; i < 8; ++i) {
          float p = fast_tanh(q4[0] + kkf[i][0]) * vvf.x;
          p = fmaf(fast_tanh(q4[1] + kkf[i][1]), vvf.y, p);
          p = fmaf(fast_tanh(q4[2] + kkf[i][2]), vvf.z, p);
          p = fmaf(fast_tanh(q4[3] + kkf[i][3]), vvf.w, p);
          #pragma unroll
          for (int m = 1; m < 64; m <<= 1) p += __shfl_xor(p, m, 64);
          if (lane == 0) lwsh[wv * 8 + i] = fast_exp(p);
        }
      }
      __syncthreads();
      // den partial -> atomicAdd
      if (tid < 64) {
        float p = lwsh[tid];
        #pragma unroll
        for (int m = 1; m < 64; m <<= 1) p += __shfl_xor(p, m, 64);
        if (tid == 0) atomicAdd(denb + (t & 1) * B + b, p);
      }
      // zero next step's accumulators (barrier-separated from readers/writers)
      if (tid < 128)
        ast(ctxb + (size_t)((t + 1) & 1) * B * HID + b * HID + qt * 128 + tid, 0.f);
      if (qt == 0 && tid == 0) ast(denb + ((t + 1) & 1) * B + b, 0.f);
      // ctx partial over 64 enc2 rows -> atomicAdd (fp32 accumulate)
      {
        const unsigned short* erow = enc2 + ((size_t)(b * TE) + qt * 64) * HID + tid;
        float a0 = 0.f, a1 = 0.f, a2 = 0.f, a3 = 0.f;
        #pragma unroll
        for (int e = 0; e < 64; e += 4) {
          a0 = fmaf(lwsh[e],     bfu(erow[(size_t)e * HID]),       a0);
          a1 = fmaf(lwsh[e + 1], bfu(erow[(size_t)(e + 1) * HID]), a1);
          a2 = fmaf(lwsh[e + 2], bfu(erow[(size_t)(e + 2) * HID]), a2);
          a3 = fmaf(lwsh[e + 3], bfu(erow[(size_t)(e + 3) * HID]), a3);
        }
        atomicAdd(ctxb + (size_t)(t & 1) * B * HID + b * HID + tid,
                  (a0 + a1) + (a2 + a3));
      }
    }
    ++seq; gridbar(flags, seq, bid, tid);

    // ================= PB: gates + LSTM update =================
    {
      float* hnext = hbuf + (size_t)((t + 1) & 1) * B * HID;
      const float* ctxcur = ctxb + (size_t)(t & 1) * B * HID;
      const unsigned* hpkc = hpk + (size_t)(t & 1) * B * 256;
      if (tid < 16) dsh[tid] = ald(denb + (t & 1) * B + bg * 16 + tid);
      __syncthreads();
      // stage all 16 batches: x plain fp32 | ctx sc1 fp32 *rcp(den) | h sc1 bf16x2
      #pragma unroll
      for (int bb = 0; bb < 16; ++bb) {
        const int bgl = bg * 16 + bb;
        if (tid < 256) {
          const int d = 2 * tid;
          const float li = __builtin_amdgcn_rcpf(dsh[bb]);
          float2 cv = ald2(ctxcur + (size_t)bgl * HID + d);
          ilds[bb][64 + d] = cv.x * li;
          ilds[bb][65 + d] = cv.y * li;
          if (tid < 32) {  // x: read-only input -> plain cached loads
            float2 xv = *(const float2*)&x[((size_t)bgl * T + t) * IN_DIM + 2 * tid];
            ilds[bb][2 * tid] = xv.x;
            ilds[bb][2 * tid + 1] = xv.y;
          }
        } else {
          const int d2 = tid - 256;  // 0..255
          unsigned hp2 = aldu(hpkc + (size_t)bgl * 256 + d2);
          ilds[bb][576 + 2 * d2] = bflo(hp2);
          ilds[bb][577 + 2 * d2] = bfhi(hp2);
        }
      }
      __syncthreads();
      #pragma unroll
      for (int bb = 0; bb < 16; ++bb) {
        const float* ib = &ilds[bb][ks * 68];
        float a0 = 0.f;
        #pragma unroll
        for (int i = 0; i < 17; ++i) {
          float4 iv = ((const float4*)ib)[i];
          a0 = fmaf(wreg[4 * i + 0], iv.x, a0);
          a0 = fmaf(wreg[4 * i + 1], iv.y, a0);
          a0 = fmaf(wreg[4 * i + 2], iv.z, a0);
          a0 = fmaf(wreg[4 * i + 3], iv.w, a0);
        }
        parts[bb][ks][r_loc] = a0;
      }
      __syncthreads();
      {
        const int bbl = tid >> 5, rr = tid & 31;
        float s = blds[rr];
        #pragma unroll
        for (int j = 0; j < 16; ++j) s += parts[bbl][j][rr];
        glds[bbl][rr] = s;
      }
      __syncthreads();
      if (tid < 128) {
        const int bbl = tid >> 3, hl = tid & 7;
        const int bb2 = bg * 16 + bbl, hu = rg * 8 + hl;
        const float gi = glds[bbl][hl],      gf = glds[bbl][8 + hl];
        const float gg = glds[bbl][16 + hl], go = glds[bbl][24 + hl];
        const float cold = cbuf[bb2 * HID + hu];  // block-private: plain cached ok
        const float cn = fast_sig(gf) * cold + fast_sig(gi) * fast_tanh(gg);
        const float hn = fast_sig(go) * fast_tanh(cn);
        cbuf[bb2 * HID + hu] = cn;
        ast(&hnext[bb2 * HID + hu], hn);            // fp32 for PA
        const float ho = __shfl_xor(hn, 1, 64);     // pack bf16 pair for next PB
        if ((hl & 1) == 0)
          astu(hpk + (size_t)((t + 1) & 1) * B * 256 + bb2 * 256 + rg * 4 + (hl >> 1),
               f2bf(hn) | (f2bf(ho) << 16));
      }
    }
    ++seq; gridbar(flags, seq, bid, tid);
  }

  // ---------------- epilogue: out(127) from h_128 (hbuf slot 0) ----------------
  if (qt == 0) {
    hsh[tid] = ald(hbuf + (size_t)b * HID + tid);
    __syncthreads();
    const int o = tid >> 3, c = tid & 7;
    const unsigned short* wr = Wfc2 + (size_t)o * HID;
    float oa = 0.f;
    #pragma unroll
    for (int j = 0; j < 8; ++j) {
      const int jj = c * 64 + ((j + c) & 7) * 8;
      uint4 w8 = *(const uint4*)(wr + jj);
      const float* hp = &hsh[jj];
      oa = fmaf(bflo(w8.x), hp[0], oa); oa = fmaf(bfhi(w8.x), hp[1], oa);
      oa = fmaf(bflo(w8.y), hp[2], oa); oa = fmaf(bfhi(w8.y), hp[3], oa);
      oa = fmaf(bflo(w8.z), hp[4], oa); oa = fmaf(bfhi(w8.z), hp[5], oa);
      oa = fmaf(bflo(w8.w), hp[6], oa); oa = fmaf(bfhi(w8.w), hp[7], oa);
    }
    oa += __shfl_xor(oa, 1, 64); oa += __shfl_xor(oa, 2, 64);
    oa += __shfl_xor(oa, 4, 64);
    if (c == 0) out[((size_t)b * T + 127) * OUTD + o] = oa + bfc[o];
  }
}

extern "C" void kernel_launch(void* const* d_in, const int* in_sizes, int n_in,
                              void* d_out, int out_size, void* d_ws, size_t ws_size,
                              hipStream_t stream) {
  const float* x   = (const float*)d_in[0];
  const float* enc = (const float*)d_in[1];
  const float* Wq  = (const float*)d_in[2];
  const float* Wk  = (const float*)d_in[3];
  const float* v   = (const float*)d_in[4];
  const float* Wih = (const float*)d_in[5];
  const float* Whh = (const float*)d_in[6];
  const float* bih = (const float*)d_in[7];
  const float* bhh = (const float*)d_in[8];
  const float* Wfc = (const float*)d_in[9];
  const float* bfc = (const float*)d_in[10];

  // ws layout (~26.3 MB)
  unsigned short* enc2  = (unsigned short*)d_ws;          // B*TE*HID
  unsigned short* keys2 = enc2 + (size_t)B * TE * HID;    // B*TE*ATTN
  unsigned short* Wq2   = keys2 + (size_t)B * TE * ATTN;  // ATTN*HID
  unsigned short* Wfc2  = Wq2 + ATTN * HID;               // OUTD*HID
  float* hbuf = (float*)(Wfc2 + OUTD * HID);  // 2*B*HID fp32
  float* cbuf = hbuf + 2 * B * HID;           // B*HID
  float* ctxb = cbuf + B * HID;               // 2*B*HID (dbuf accumulators)
  float* denb = ctxb + 2 * B * HID;           // 2*B
  unsigned* hpk = (unsigned*)(denb + 2 * B);  // 2*B*256 (packed bf16 h, dbuf)
  int* flags = (int*)(hpk + 2 * B * 256);     // 256

  // zero hbuf|cbuf|ctxb|denb|hpk|flags in one contiguous stream-ordered memset
  const size_t zero_units = 2 * B * HID + B * HID + 2 * B * HID + 2 * B +
                            2 * B * 256 + 256;
  hipMemsetAsync(hbuf, 0, zero_units * 4, stream);

  cvt_kernel<<<dim3(512), dim3(256), 0, stream>>>(enc, enc2, B * TE * HID);
  cvt_kernel<<<dim3(64), dim3(256), 0, stream>>>(Wq, Wq2, ATTN * HID);
  cvt_kernel<<<dim3(32), dim3(256), 0, stream>>>(Wfc, Wfc2, OUTD * HID);
  keys_kernel<<<dim3(1024), dim3(256), 0, stream>>>(enc, Wk, keys2);
  main_kernel<<<dim3(G), dim3(BS), 0, stream>>>(
      x, v, Wih, Whh, bih, bhh, bfc, enc2, keys2, Wq2, Wfc2,
      hbuf, cbuf, ctxb, denb, hpk, flags, (float*)d_out);
}

// Round 7
// 4283.731 us; speedup vs baseline: 2.3162x; 1.3399x over previous
//
#include <hip/hip_runtime.h>

// LSTM decoder w/ Bahdanau attention, MI355X.
// Persistent grid-synchronized kernel, 256 blocks x 512 threads (1 block/CU).
// TWO grid barriers per step:
//   PA (block=(batch b, quarter qt)): stage h[b](fp32)->LDS; q=h@Wq2^T (bf16, L2-res);
//       out(t-1)=h@Wfc2^T (qt==0); energies tanh(q+keys2_reg)*v; unnormalized exp ->
//       den atomicAdd + ctx atomicAdd (fp32, zero-ahead dbuf).
//   PB (block=(row-slice rg, batch-group bg)): MFMA gates GEMM:
//       M=16 batches x N=32 rows x K=1088, bf16 16x16x32. Weights = B-frags in VGPRs
//       (step-invariant, hi+lo bf16 split cancels weight rounding); inputs staged once
//       to a lane-distributed LDS A-tile (x pre-packed bf16, h from hpk bf16, ctx
//       cvt at staging); 8 waves = 2 N-tiles x 4 K-slices; LDS reduce; pointwise.
// Lessons:
// R1: __threadfence/acquire => buffer_wbl2/inv per op => 65us barriers. RELAXED
//     agent-scope (sc1) atomics for all cross-block mutable data.
// R4: single-counter barrier collapses (256 spinners); fp32 Wq per-block thrashes L2.
// R5: PB staged 43MB/step of L2-bypassing sc1 reads -> ctx pre-summed, h bf16-packed.
// R6: VALU-loop gates GEMM is LDS-broadcast-bound: 272 ds_read_b128/thread = 11us/step
//     moving 2.2MB to use 70KB. Fix: MFMA with lane-distributed A-tile (this round).

#define B 64
#define T 128
#define IN_DIM 64
#define TE 256
#define HID 512
#define ATTN 256
#define OUTD 64
#define G 256
#define BS 512

typedef __attribute__((ext_vector_type(8))) short short8;
typedef __attribute__((ext_vector_type(4))) float f32x4;

__device__ __forceinline__ float fast_exp(float x) {
  return __builtin_amdgcn_exp2f(x * 1.44269504f);
}
__device__ __forceinline__ float fast_tanh(float x) {
  float ax = fabsf(x);
  float z = __builtin_amdgcn_exp2f(ax * -2.885390082f);  // e^{-2|x|}
  float r = (1.f - z) * __builtin_amdgcn_rcpf(1.f + z);
  return copysignf(r, x);
}
__device__ __forceinline__ float fast_sig(float x) {
  float z = __builtin_amdgcn_exp2f(x * -1.44269504f);    // e^{-x}
  return __builtin_amdgcn_rcpf(1.f + z);
}
__device__ __forceinline__ float bfu(unsigned short u) {
  return __uint_as_float((unsigned)u << 16);
}
__device__ __forceinline__ float bflo(unsigned u) { return __uint_as_float(u << 16); }
__device__ __forceinline__ float bfhi(unsigned u) {
  return __uint_as_float(u & 0xffff0000u);
}
__device__ __forceinline__ unsigned f2bf(float f) {  // RNE bf16 bits
  unsigned u = __float_as_uint(f);
  return (u + 0x7fff + ((u >> 16) & 1)) >> 16;
}

// Relaxed agent-scope atomics: global_load/store ... sc1 (coherence point, no L2 flush).
__device__ __forceinline__ float ald(const float* p) {
  return __hip_atomic_load((float*)p, __ATOMIC_RELAXED, __HIP_MEMORY_SCOPE_AGENT);
}
__device__ __forceinline__ float2 ald2(const float* p) {
  double d = __hip_atomic_load((const double*)p, __ATOMIC_RELAXED,
                               __HIP_MEMORY_SCOPE_AGENT);
  union { double d; float2 f; } u; u.d = d; return u.f;
}
__device__ __forceinline__ unsigned aldu(const unsigned* p) {
  return __hip_atomic_load(p, __ATOMIC_RELAXED, __HIP_MEMORY_SCOPE_AGENT);
}
__device__ __forceinline__ void ast(float* p, float v) {
  __hip_atomic_store(p, v, __ATOMIC_RELAXED, __HIP_MEMORY_SCOPE_AGENT);
}
__device__ __forceinline__ void astu(unsigned* p, unsigned v) {
  __hip_atomic_store(p, v, __ATOMIC_RELAXED, __HIP_MEMORY_SCOPE_AGENT);
}

// Flag-array barrier (R3/R6-proven). Signed >= : 0xAA poison is negative.
__device__ __forceinline__ void gridbar(int* flags, int seq, int bid, int tid) {
  asm volatile("s_waitcnt vmcnt(0)" ::: "memory");
  __syncthreads();
  if (tid == 0)
    __hip_atomic_store(&flags[bid], seq, __ATOMIC_RELAXED, __HIP_MEMORY_SCOPE_AGENT);
  if (tid < G) {
    while (__hip_atomic_load(&flags[tid], __ATOMIC_RELAXED,
                             __HIP_MEMORY_SCOPE_AGENT) < seq) {
      __builtin_amdgcn_s_sleep(1);
    }
  }
  __syncthreads();
}

// fp32 -> bf16 (RNE)
__global__ void cvt_kernel(const float* __restrict__ src,
                           unsigned short* __restrict__ dst, int n) {
  for (int i = blockIdx.x * blockDim.x + threadIdx.x; i < n;
       i += gridDim.x * blockDim.x)
    dst[i] = (unsigned short)f2bf(src[i]);
}
// fp32 pairs -> packed bf16x2
__global__ void pack2_kernel(const float* __restrict__ src,
                             unsigned* __restrict__ dst, int n2) {
  for (int i = blockIdx.x * blockDim.x + threadIdx.x; i < n2;
       i += gridDim.x * blockDim.x)
    dst[i] = f2bf(src[2 * i]) | (f2bf(src[2 * i + 1]) << 16);
}

// ---- keys2[b][e][a] = bf16( sum_k enc[b][e][k] * Wk[a][k] ) ----
__global__ __launch_bounds__(256, 2) void keys_kernel(
    const float* __restrict__ enc, const float* __restrict__ Wk,
    unsigned short* __restrict__ keys2) {
  __shared__ float et[16][512];
  __shared__ float wk[32][256];
  const int tid = threadIdx.x;
  const int b = blockIdx.x >> 4;
  const int e0 = (blockIdx.x & 15) * 16;

  for (int p = 0; p < 8; ++p) {
    int i = p * 256 + tid;
    int e = i >> 7, kq = i & 127;
    float4 vv = *(const float4*)&enc[((size_t)(b * TE + e0 + e)) * HID + kq * 4];
    *(float4*)&et[e][kq * 4] = vv;
  }

  float acc[8][2];
  #pragma unroll
  for (int i = 0; i < 8; ++i) { acc[i][0] = 0.f; acc[i][1] = 0.f; }
  const int a0 = tid & 127;
  const int eh = (tid >> 7) * 8;

  for (int kc = 0; kc < 512; kc += 32) {
    __syncthreads();
    for (int p = 0; p < 8; ++p) {
      int i = p * 256 + tid;
      int a = i >> 3, j4 = (i & 7) * 4;
      float4 w4 = *(const float4*)&Wk[(size_t)a * HID + kc + j4];
      wk[j4 + 0][a] = w4.x; wk[j4 + 1][a] = w4.y;
      wk[j4 + 2][a] = w4.z; wk[j4 + 3][a] = w4.w;
    }
    __syncthreads();
    for (int k = 0; k < 32; ++k) {
      float w0 = wk[k][a0], w1 = wk[k][a0 + 128];
      #pragma unroll
      for (int i = 0; i < 8; ++i) {
        float ev = et[eh + i][kc + k];
        acc[i][0] = fmaf(ev, w0, acc[i][0]);
        acc[i][1] = fmaf(ev, w1, acc[i][1]);
      }
    }
  }
  #pragma unroll
  for (int i = 0; i < 8; ++i)
    #pragma unroll
    for (int h = 0; h < 2; ++h)
      keys2[((size_t)(b * TE + e0 + eh + i)) * ATTN + a0 + 128 * h] =
          (unsigned short)f2bf(acc[i][h]);
}

__global__ __launch_bounds__(BS, 2) void main_kernel(
    const float* __restrict__ v,
    const float* __restrict__ Wih, const float* __restrict__ Whh,
    const float* __restrict__ bih, const float* __restrict__ bhh,
    const float* __restrict__ bfc,
    const unsigned short* __restrict__ enc2, const unsigned short* __restrict__ keys2,
    const unsigned short* __restrict__ Wq2, const unsigned short* __restrict__ Wfc2,
    const unsigned* __restrict__ x2pk,
    float* hbuf, float* cbuf, float* ctxb, float* denb, unsigned* hpk,
    int* flags, float* out) {
  const int bid = blockIdx.x, tid = threadIdx.x;
  const int b = bid >> 2, qt = bid & 3;        // PA role
  const int rg = bid >> 2, bg = bid & 3;       // PB role
  const int lane = tid & 63, wv = tid >> 6;

  // LDS (48.3 KB total)
  __shared__ unsigned alds[34 * 256];   // 34.8 KB A-tile [kc][m 16][16 dw, xor-swizzled]
  __shared__ float pc[2 * 4 * 16 * 17]; // 8.7 KB mfma partials [nt][kq][m][n pad17]
  __shared__ float glds[16 * 33];       // gate values [m][r pad33]
  __shared__ float hsh[HID];            // PA: staged h[b] (fp32)
  __shared__ float qsh[320];            // PA: q, swizzled idx r+(r>>2)
  __shared__ float lwsh[64];            // PA: exp weights (this quarter's rows)
  __shared__ float dsh[16];             // PB: den per batch in group
  __shared__ float blds[32];            // PB: biases

  // ---- prologue: persistent registers ----
  if (tid < 32) {
    const int gr2 = (tid >> 3) * 512 + rg * 8 + (tid & 7);
    blds[tid] = bih[gr2] + bhh[gr2];
  }
  const float4 vvf = *(const float4*)&v[lane * 4];
  float kkf[8][4];  // step-invariant keys in VGPRs (PA)
  #pragma unroll
  for (int i = 0; i < 8; ++i) {
    const unsigned short* kr =
        keys2 + ((size_t)(b * TE) + qt * 64 + wv * 8 + i) * ATTN + lane * 4;
    uint2 k4 = *(const uint2*)kr;
    kkf[i][0] = bflo(k4.x); kkf[i][1] = bfhi(k4.x);
    kkf[i][2] = bflo(k4.y); kkf[i][3] = bfhi(k4.y);
  }
  // PB mfma geometry: wave = (nt = N-tile of 16 rows, kq = K-slice)
  const int mL = lane & 15, qL = lane >> 4;
  const int nt = wv >> 2, kq = wv & 3;
  const int kstart = (kq < 2) ? kq * 9 : 18 + (kq - 2) * 8;  // 9,9,8,8 chunks of K=32
  const int nch = (kq < 2) ? 9 : 8;
  const int aoff = mL * 16 + ((qL * 4) ^ (((mL >> 1) & 3) * 4));  // A-frag dword offset
  // B-fragments (weights) in VGPRs, step-invariant: hi + lo bf16 split
  short8 bh[9], bl[9];
  {
    const int rloc = nt * 16 + mL;  // row 0..31 of this block
    const int grow2 = (rloc >> 3) * 512 + rg * 8 + (rloc & 7);
    #pragma unroll
    for (int c = 0; c < 9; ++c) {
      unsigned uh[4] = {0, 0, 0, 0}, ul[4] = {0, 0, 0, 0};
      if (c < nch) {
        const int kc = kstart + c;
        #pragma unroll
        for (int j = 0; j < 8; ++j) {
          const int k = kc * 32 + qL * 8 + j;
          const float w = (k < 576) ? Wih[(size_t)grow2 * 576 + k]
                                    : Whh[(size_t)grow2 * 512 + (k - 576)];
          const unsigned hi = f2bf(w);
          const float lo = w - __uint_as_float(hi << 16);
          uh[j >> 1] |= hi << (16 * (j & 1));
          ul[j >> 1] |= f2bf(lo) << (16 * (j & 1));
        }
      }
      uint4 th; th.x = uh[0]; th.y = uh[1]; th.z = uh[2]; th.w = uh[3];
      uint4 tl; tl.x = ul[0]; tl.y = ul[1]; tl.z = ul[2]; tl.w = ul[3];
      bh[c] = __builtin_bit_cast(short8, th);
      bl[c] = __builtin_bit_cast(short8, tl);
    }
  }

  int seq = 0;

  for (int t = 0; t < T; ++t) {
    // ================= PA: attention in-block =================
    {
      const float* hprev = hbuf + (size_t)(t & 1) * B * HID;
      hsh[tid] = ald(hprev + (size_t)b * HID + tid);
      __syncthreads();
      if (qt == 0 && t >= 1) {  // out(t-1), rotated k-chunks
        const int o = tid >> 3, c = tid & 7;
        const unsigned short* wr = Wfc2 + (size_t)o * HID;
        float oa = 0.f;
        #pragma unroll
        for (int j = 0; j < 8; ++j) {
          const int jj = c * 64 + ((j + c) & 7) * 8;
          uint4 w8 = *(const uint4*)(wr + jj);
          const float* hp = &hsh[jj];
          oa = fmaf(bflo(w8.x), hp[0], oa); oa = fmaf(bfhi(w8.x), hp[1], oa);
          oa = fmaf(bflo(w8.y), hp[2], oa); oa = fmaf(bfhi(w8.y), hp[3], oa);
          oa = fmaf(bflo(w8.z), hp[4], oa); oa = fmaf(bfhi(w8.z), hp[5], oa);
          oa = fmaf(bflo(w8.w), hp[6], oa); oa = fmaf(bfhi(w8.w), hp[7], oa);
        }
        oa += __shfl_xor(oa, 1, 64); oa += __shfl_xor(oa, 2, 64);
        oa += __shfl_xor(oa, 4, 64);
        if (c == 0) out[((size_t)b * T + (t - 1)) * OUTD + o] = oa + bfc[o];
      }
      {  // q[256] = h @ Wq2^T: 2 threads/row
        const int r = tid >> 1, c2 = tid & 1;
        const unsigned short* wr = Wq2 + (size_t)r * HID + c2 * 256;
        const float* hb = &hsh[c2 * 256];
        float qa = 0.f;
        #pragma unroll 8
        for (int j = 0; j < 32; ++j) {
          uint4 w8 = ((const uint4*)wr)[j];
          const float* hp = hb + j * 8;
          qa = fmaf(bflo(w8.x), hp[0], qa); qa = fmaf(bfhi(w8.x), hp[1], qa);
          qa = fmaf(bflo(w8.y), hp[2], qa); qa = fmaf(bfhi(w8.y), hp[3], qa);
          qa = fmaf(bflo(w8.z), hp[4], qa); qa = fmaf(bfhi(w8.z), hp[5], qa);
          qa = fmaf(bflo(w8.w), hp[6], qa); qa = fmaf(bfhi(w8.w), hp[7], qa);
        }
        qa += __shfl_xor(qa, 1, 64);
        if (c2 == 0) qsh[r + (r >> 2)] = qa;
      }
      __syncthreads();
      {  // energies
        float q4[4];
        #pragma unroll
        for (int j = 0; j < 4; ++j) q4[j] = qsh[5 * lane + j];
        #pragma unroll
        for (int i = 0; i < 8; ++i) {
          float p = fast_tanh(q4[0] + kkf[i][0]) * vvf.x;
          p = fmaf(fast_tanh(q4[1] + kkf[i][1]), vvf.y, p);
          p = fmaf(fast_tanh(q4[2] + kkf[i][2]), vvf.z, p);
          p = fmaf(fast_tanh(q4[3] + kkf[i][3]), vvf.w, p);
          #pragma unroll
          for (int m = 1; m < 64; m <<= 1) p += __shfl_xor(p, m, 64);
          if (lane == 0) lwsh[wv * 8 + i] = fast_exp(p);
        }
      }
      __syncthreads();
      if (tid < 64) {  // den partial
        float p = lwsh[tid];
        #pragma unroll
        for (int m = 1; m < 64; m <<= 1) p += __shfl_xor(p, m, 64);
        if (tid == 0) atomicAdd(denb + (t & 1) * B + b, p);
      }
      // zero next step's accumulators (barrier-separated)
      if (tid < 128)
        ast(ctxb + (size_t)((t + 1) & 1) * B * HID + b * HID + qt * 128 + tid, 0.f);
      if (qt == 0 && tid == 0) ast(denb + ((t + 1) & 1) * B + b, 0.f);
      {  // ctx partial over 64 enc2 rows -> atomicAdd
        const unsigned short* erow = enc2 + ((size_t)(b * TE) + qt * 64) * HID + tid;
        float a0 = 0.f, a1 = 0.f, a2 = 0.f, a3 = 0.f;
        #pragma unroll
        for (int e = 0; e < 64; e += 4) {
          a0 = fmaf(lwsh[e],     bfu(erow[(size_t)e * HID]),       a0);
          a1 = fmaf(lwsh[e + 1], bfu(erow[(size_t)(e + 1) * HID]), a1);
          a2 = fmaf(lwsh[e + 2], bfu(erow[(size_t)(e + 2) * HID]), a2);
          a3 = fmaf(lwsh[e + 3], bfu(erow[(size_t)(e + 3) * HID]), a3);
        }
        atomicAdd(ctxb + (size_t)(t & 1) * B * HID + b * HID + tid,
                  (a0 + a1) + (a2 + a3));
      }
    }
    ++seq; gridbar(flags, seq, bid, tid);

    // ================= PB: MFMA gates + LSTM update =================
    {
      float* hnext = hbuf + (size_t)((t + 1) & 1) * B * HID;
      const float* ctxcur = ctxb + (size_t)(t & 1) * B * HID;
      const unsigned* hpkc = hpk + (size_t)(t & 1) * B * 256;
      if (tid < 16) dsh[tid] = ald(denb + (t & 1) * B + bg * 16 + tid);
      __syncthreads();
      // ---- stage A-tile: batch m = tid>>5, 17 packed dwords per thread ----
      {
        const int sm = tid >> 5, ss = tid & 31;
        const int bgl = bg * 16 + sm;
        const int swm = ((sm >> 1) & 3) * 4;
        const float li = __builtin_amdgcn_rcpf(dsh[sm]);
        const int dcol = (ss & 15) ^ swm;
        {  // p=0: x (pre-packed bf16)
          unsigned pk = x2pk[((size_t)bgl * T + t) * 32 + ss];
          alds[(ss >> 4) * 256 + sm * 16 + dcol] = pk;
        }
        #pragma unroll
        for (int p = 1; p <= 8; ++p) {  // ctx: fp32 pairs -> *li -> bf16 pack
          const int i = ss + 32 * p;
          float2 cv = ald2(ctxcur + (size_t)bgl * HID + (2 * i - 64));
          unsigned pk = f2bf(cv.x * li) | (f2bf(cv.y * li) << 16);
          alds[(i >> 4) * 256 + sm * 16 + dcol] = pk;
        }
        #pragma unroll
        for (int p = 9; p <= 16; ++p) {  // h: already packed bf16
          const int i = ss + 32 * p;
          unsigned pk = aldu(hpkc + (size_t)bgl * 256 + (i - 288));
          alds[(i >> 4) * 256 + sm * 16 + dcol] = pk;
        }
      }
      __syncthreads();
      // ---- MFMA: 8-9 chunks, hi+lo weight split ----
      {
        f32x4 ach = {0.f, 0.f, 0.f, 0.f}, acl = {0.f, 0.f, 0.f, 0.f};
        #pragma unroll
        for (int c = 0; c < 9; ++c) {
          if (c < nch) {
            const uint4 av = *(const uint4*)&alds[(kstart + c) * 256 + aoff];
            const short8 a8 = __builtin_bit_cast(short8, av);
            ach = __builtin_amdgcn_mfma_f32_16x16x32_bf16(a8, bh[c], ach, 0, 0, 0);
            acl = __builtin_amdgcn_mfma_f32_16x16x32_bf16(a8, bl[c], acl, 0, 0, 0);
          }
        }
        #pragma unroll
        for (int rr = 0; rr < 4; ++rr)
          pc[((nt * 4 + kq) * 16 + qL * 4 + rr) * 17 + mL] = ach[rr] + acl[rr];
      }
      __syncthreads();
      {  // reduce 4 K-slices + bias -> glds[m][r]
        const int r2 = tid >> 4, mb = tid & 15;
        const int pbase = ((r2 >> 4) * 64 + mb) * 17 + (r2 & 15);
        float s = blds[r2] + ((pc[pbase] + pc[pbase + 272]) +
                              (pc[pbase + 544] + pc[pbase + 816]));
        glds[mb * 33 + r2] = s;
      }
      __syncthreads();
      if (tid < 128) {  // pointwise LSTM
        const int bbl = tid >> 3, hl = tid & 7;
        const int bb2 = bg * 16 + bbl, hu = rg * 8 + hl;
        const float gi = glds[bbl * 33 + hl],      gf = glds[bbl * 33 + 8 + hl];
        const float gg = glds[bbl * 33 + 16 + hl], go = glds[bbl * 33 + 24 + hl];
        const float cold = cbuf[bb2 * HID + hu];  // block-private: plain cached ok
        const float cn = fast_sig(gf) * cold + fast_sig(gi) * fast_tanh(gg);
        const float hn = fast_sig(go) * fast_tanh(cn);
        cbuf[bb2 * HID + hu] = cn;
        ast(&hnext[bb2 * HID + hu], hn);            // fp32 for PA
        const float ho = __shfl_xor(hn, 1, 64);     // bf16 pair for next PB
        if ((hl & 1) == 0)
          astu(hpk + (size_t)((t + 1) & 1) * B * 256 + bb2 * 256 + rg * 4 + (hl >> 1),
               f2bf(hn) | (f2bf(ho) << 16));
      }
    }
    ++seq; gridbar(flags, seq, bid, tid);
  }

  // ---------------- epilogue: out(127) from h_128 (hbuf slot 0) ----------------
  if (qt == 0) {
    hsh[tid] = ald(hbuf + (size_t)b * HID + tid);
    __syncthreads();
    const int o = tid >> 3, c = tid & 7;
    const unsigned short* wr = Wfc2 + (size_t)o * HID;
    float oa = 0.f;
    #pragma unroll
    for (int j = 0; j < 8; ++j) {
      const int jj = c * 64 + ((j + c) & 7) * 8;
      uint4 w8 = *(const uint4*)(wr + jj);
      const float* hp = &hsh[jj];
      oa = fmaf(bflo(w8.x), hp[0], oa); oa = fmaf(bfhi(w8.x), hp[1], oa);
      oa = fmaf(bflo(w8.y), hp[2], oa); oa = fmaf(bfhi(w8.y), hp[3], oa);
      oa = fmaf(bflo(w8.z), hp[4], oa); oa = fmaf(bfhi(w8.z), hp[5], oa);
      oa = fmaf(bflo(w8.w), hp[6], oa); oa = fmaf(bfhi(w8.w), hp[7], oa);
    }
    oa += __shfl_xor(oa, 1, 64); oa += __shfl_xor(oa, 2, 64);
    oa += __shfl_xor(oa, 4, 64);
    if (c == 0) out[((size_t)b * T + 127) * OUTD + o] = oa + bfc[o];
  }
}

extern "C" void kernel_launch(void* const* d_in, const int* in_sizes, int n_in,
                              void* d_out, int out_size, void* d_ws, size_t ws_size,
                              hipStream_t stream) {
  const float* x   = (const float*)d_in[0];
  const float* enc = (const float*)d_in[1];
  const float* Wq  = (const float*)d_in[2];
  const float* Wk  = (const float*)d_in[3];
  const float* v   = (const float*)d_in[4];
  const float* Wih = (const float*)d_in[5];
  const float* Whh = (const float*)d_in[6];
  const float* bih = (const float*)d_in[7];
  const float* bhh = (const float*)d_in[8];
  const float* Wfc = (const float*)d_in[9];
  const float* bfc = (const float*)d_in[10];

  // ws layout (~28.4 MB)
  unsigned short* enc2  = (unsigned short*)d_ws;          // B*TE*HID
  unsigned short* keys2 = enc2 + (size_t)B * TE * HID;    // B*TE*ATTN
  unsigned short* Wq2   = keys2 + (size_t)B * TE * ATTN;  // ATTN*HID
  unsigned short* Wfc2  = Wq2 + ATTN * HID;               // OUTD*HID
  float* hbuf = (float*)(Wfc2 + OUTD * HID);  // 2*B*HID fp32
  float* cbuf = hbuf + 2 * B * HID;           // B*HID
  float* ctxb = cbuf + B * HID;               // 2*B*HID (dbuf accumulators)
  float* denb = ctxb + 2 * B * HID;           // 2*B
  unsigned* hpk = (unsigned*)(denb + 2 * B);  // 2*B*256 packed bf16 h (dbuf)
  int* flags = (int*)(hpk + 2 * B * 256);     // 256
  unsigned* x2pk = (unsigned*)(flags + 256);  // B*T*32 packed bf16 x

  // zero hbuf|cbuf|ctxb|denb|hpk|flags (contiguous) every call
  const size_t zero_units = 2 * B * HID + B * HID + 2 * B * HID + 2 * B +
                            2 * B * 256 + 256;
  hipMemsetAsync(hbuf, 0, zero_units * 4, stream);

  cvt_kernel<<<dim3(512), dim3(256), 0, stream>>>(enc, enc2, B * TE * HID);
  cvt_kernel<<<dim3(64), dim3(256), 0, stream>>>(Wq, Wq2, ATTN * HID);
  cvt_kernel<<<dim3(32), dim3(256), 0, stream>>>(Wfc, Wfc2, OUTD * HID);
  pack2_kernel<<<dim3(128), dim3(256), 0, stream>>>(x, x2pk, B * T * 32);
  keys_kernel<<<dim3(1024), dim3(256), 0, stream>>>(enc, Wk, keys2);
  main_kernel<<<dim3(G), dim3(BS), 0, stream>>>(
      v, Wih, Whh, bih, bhh, bfc, enc2, keys2, Wq2, Wfc2, x2pk,
      hbuf, cbuf, ctxb, denb, hpk, flags, (float*)d_out);
}